// Round 5
// baseline (58.661 us; speedup 1.0000x reference)
//
#include <hip/hip_runtime.h>

// MultiHuberLoss: input [65536, 1000] f32, target [65536] i32 -> scalar f32
// Reference: m = (c==tgt[r]) ? x : -x ; h=1-m ; loss = (m>=-1)? max(0,h)^2 : -4m
// Identity:  loss = f(h) = hc*(2h-hc), hc = clamp(h,0,2)   [0 / h^2 / 4h-4 pieces]
// Decomposition: sum = sum_all f(1+x)  +  sum_rows [ f(1-x_t) - f(1+x_t) ]
//   -> hot loop is target-free (4 VALU/elem), correction is 65536 gathers.

typedef float f4 __attribute__((ext_vector_type(4)));

constexpr int N_ROWS = 65536;
constexpr int N_COLS = 1000;
constexpr int F4_PER_ROW = N_COLS / 4;                    // 250
constexpr int TOTAL_F4 = N_ROWS * F4_PER_ROW;             // 16,384,000

constexpr int BLOCK = 256;
constexpr int MAIN_GRID = 2000;                           // 2000*256=512,000 threads
constexpr int CORR_GRID = 64;                             // 64*256=16,384 threads, 4 rows each
constexpr int STRIDE_F4 = MAIN_GRID * BLOCK;              // 512,000
constexpr int ITERS = TOTAL_F4 / STRIDE_F4;               // 32 exactly (no tail)
constexpr int BATCH = 8;

__device__ __forceinline__ float huber_f(float h) {
    // f(h) = 0 (h<=0) ; h^2 (0<=h<=2) ; 4h-4 (h>=2)  ==  hc*(2h-hc), hc=clamp(h,0,2)
    float hc = fmaxf(fminf(h, 2.0f), 0.0f);               // v_med3_f32
    return hc * fmaf(h, 2.0f, -hc);
}

__global__ __launch_bounds__(BLOCK) void mhl_kernel(const f4* __restrict__ in,
                                                    const float* __restrict__ in_f,
                                                    const int* __restrict__ tgt,
                                                    float* __restrict__ out) {
    float acc = 0.0f;

    if (blockIdx.x < CORR_GRID) {
        // ---- correction pass: one gather per row ----
        int tid = blockIdx.x * BLOCK + threadIdx.x;       // 0..16383
#pragma unroll
        for (int k = 0; k < 4; ++k) {
            int r = tid + k * (CORR_GRID * BLOCK);
            int t = tgt[r];
            float x = in_f[r * N_COLS + t];
            acc += huber_f(1.0f - x) - huber_f(1.0f + x);
        }
    } else {
        // ---- main pass: target-free stream ----
        int idx = (blockIdx.x - CORR_GRID) * BLOCK + threadIdx.x;
        int p = idx;
#pragma unroll 1
        for (int it = 0; it < ITERS / BATCH; ++it) {
            f4 v[BATCH];
#pragma unroll
            for (int j = 0; j < BATCH; ++j)
                v[j] = in[p + j * STRIDE_F4];
#pragma unroll
            for (int j = 0; j < BATCH; ++j) {
#pragma unroll
                for (int e = 0; e < 4; ++e) {
                    float h = 1.0f + v[j][e];             // v_add
                    float hc = fmaxf(fminf(h, 2.0f), 0.0f); // v_med3
                    acc = fmaf(hc, fmaf(h, 2.0f, -hc), acc); // v_fma + v_fmac
                }
            }
            p += BATCH * STRIDE_F4;
        }
    }

    // wave64 butterfly reduce
#pragma unroll
    for (int off = 32; off > 0; off >>= 1)
        acc += __shfl_down(acc, off, 64);

    __shared__ float wsum[BLOCK / 64];
    int wid = threadIdx.x >> 6;
    int lane = threadIdx.x & 63;
    if (lane == 0) wsum[wid] = acc;
    __syncthreads();

    if (threadIdx.x == 0) {
        float s = wsum[0] + wsum[1] + wsum[2] + wsum[3];
        atomicAdd(out, s * (1.0f / (float)N_ROWS));
    }
}

extern "C" void kernel_launch(void* const* d_in, const int* in_sizes, int n_in,
                              void* d_out, int out_size, void* d_ws, size_t ws_size,
                              hipStream_t stream) {
    const f4* in = (const f4*)d_in[0];
    const float* in_f = (const float*)d_in[0];
    const int* tgt = (const int*)d_in[1];
    float* out = (float*)d_out;

    // d_out is poisoned (0xAA) before timing and NOT re-poisoned between
    // replays — zero it every call (memset is graph-capture-safe).
    (void)hipMemsetAsync(out, 0, sizeof(float), stream);

    mhl_kernel<<<MAIN_GRID + CORR_GRID, BLOCK, 0, stream>>>(in, in_f, tgt, out);
}

// Round 6
// 47.399 us; speedup vs baseline: 1.2376x; 1.2376x over previous
//
#include <hip/hip_runtime.h>

// MultiHuberLoss: input [65536, 1000] f32, target [65536] i32 -> scalar f32
// Identity:  loss(h) = hc*(2h-hc), hc = clamp(h,0,2), h = 1-m   [0 / h^2 / 4h-4]
// Decomposition: sum = sum_all f(1+x) + sum_rows [ f(1-x_t) - f(1+x_t) ]
// Two kernels: main (stream + per-block partial) -> reduce (store out, no memset/atomics).

typedef float f4 __attribute__((ext_vector_type(4)));

constexpr int N_ROWS = 65536;
constexpr int N_COLS = 1000;
constexpr int F4_PER_ROW = N_COLS / 4;                    // 250
constexpr int TOTAL_F4 = N_ROWS * F4_PER_ROW;             // 16,384,000

constexpr int BLOCK = 256;
constexpr int GRID = 2000;                                // exactly co-resident (<=2048), no tail
constexpr int STRIDE_F4 = GRID * BLOCK;                   // 512,000
constexpr int ITERS = TOTAL_F4 / STRIDE_F4;               // 32 exactly
constexpr int BATCH = 8;
constexpr int ROWS_PER_BLOCK = 33;                        // ceil(65536 / 2000)

__device__ __forceinline__ float huber_f(float h) {
    float hc = fmaxf(fminf(h, 2.0f), 0.0f);               // v_med3_f32
    return hc * fmaf(h, 2.0f, -hc);
}

__global__ __launch_bounds__(BLOCK) void mhl_main(const f4* __restrict__ in,
                                                  const float* __restrict__ in_f,
                                                  const int* __restrict__ tgt,
                                                  float* __restrict__ partial) {
    float acc = 0.0f;

    // correction gathers, folded into the main blocks (latency hides under the stream):
    // block b owns rows [b*33, b*33+33) ∩ [0, 65536), one gather per thread (lanes 0..32)
    if (threadIdx.x < ROWS_PER_BLOCK) {
        int r = blockIdx.x * ROWS_PER_BLOCK + threadIdx.x;
        if (r < N_ROWS) {
            int t = tgt[r];
            float x = in_f[r * N_COLS + t];               // < 65.5M, fits int32
            acc += huber_f(1.0f - x) - huber_f(1.0f + x);
        }
    }

    // main pass: target-free stream, 4 VALU/elem
    int p = blockIdx.x * BLOCK + threadIdx.x;
#pragma unroll 1
    for (int it = 0; it < ITERS / BATCH; ++it) {
        f4 v[BATCH];
#pragma unroll
        for (int j = 0; j < BATCH; ++j)
            v[j] = in[p + j * STRIDE_F4];
#pragma unroll
        for (int j = 0; j < BATCH; ++j) {
#pragma unroll
            for (int e = 0; e < 4; ++e) {
                float h = 1.0f + v[j][e];                 // v_add
                float hc = fmaxf(fminf(h, 2.0f), 0.0f);   // v_med3
                acc = fmaf(hc, fmaf(h, 2.0f, -hc), acc);  // v_fma + v_fmac
            }
        }
        p += BATCH * STRIDE_F4;
    }

    // block reduce -> one partial per block (no atomics, no zeroed output needed)
#pragma unroll
    for (int off = 32; off > 0; off >>= 1)
        acc += __shfl_down(acc, off, 64);

    __shared__ float wsum[BLOCK / 64];
    if ((threadIdx.x & 63) == 0) wsum[threadIdx.x >> 6] = acc;
    __syncthreads();
    if (threadIdx.x == 0)
        partial[blockIdx.x] = wsum[0] + wsum[1] + wsum[2] + wsum[3];
}

__global__ __launch_bounds__(BLOCK) void mhl_reduce(const float* __restrict__ partial,
                                                    float* __restrict__ out) {
    float acc = 0.0f;
    for (int i = threadIdx.x; i < GRID; i += BLOCK)
        acc += partial[i];
#pragma unroll
    for (int off = 32; off > 0; off >>= 1)
        acc += __shfl_down(acc, off, 64);
    __shared__ float wsum[BLOCK / 64];
    if ((threadIdx.x & 63) == 0) wsum[threadIdx.x >> 6] = acc;
    __syncthreads();
    if (threadIdx.x == 0)
        out[0] = (wsum[0] + wsum[1] + wsum[2] + wsum[3]) * (1.0f / (float)N_ROWS);
}

extern "C" void kernel_launch(void* const* d_in, const int* in_sizes, int n_in,
                              void* d_out, int out_size, void* d_ws, size_t ws_size,
                              hipStream_t stream) {
    const f4* in = (const f4*)d_in[0];
    const float* in_f = (const float*)d_in[0];
    const int* tgt = (const int*)d_in[1];
    float* out = (float*)d_out;
    float* partial = (float*)d_ws;                        // 2000 floats = 8 KB of ws

    mhl_main<<<GRID, BLOCK, 0, stream>>>(in, in_f, tgt, partial);
    mhl_reduce<<<1, BLOCK, 0, stream>>>(partial, out);
}

// Round 7
// 47.253 us; speedup vs baseline: 1.2414x; 1.0031x over previous
//
#include <hip/hip_runtime.h>

// MultiHuberLoss: input [65536, 1000] f32, target [65536] i32 -> scalar f32
// Identity:  loss(h) = hc*(2h-hc), hc = clamp(h,0,2), h = 1-m   [0 / h^2 / 4h-4]
// Decomposition: sum = sum_all f(1+x) + sum_rows [ f(1-x_t) - f(1+x_t) ]
// Two kernels: main (stream + per-block partial) -> reduce (store out, no memset/atomics).

typedef float f4 __attribute__((ext_vector_type(4)));

constexpr int N_ROWS = 65536;
constexpr int N_COLS = 1000;
constexpr int F4_PER_ROW = N_COLS / 4;                    // 250
constexpr int TOTAL_F4 = N_ROWS * F4_PER_ROW;             // 16,384,000

constexpr int BLOCK = 256;
// GRID=1000: co-resident even at 4 blocks/CU (cap 1024) -> no straggler round
// regardless of VGPR count. 64000/1000 = 64 iters exactly, no tail.
constexpr int GRID = 1000;
constexpr int STRIDE_F4 = GRID * BLOCK;                   // 256,000
constexpr int ITERS = TOTAL_F4 / STRIDE_F4;               // 64 exactly
constexpr int BATCH = 8;                                  // 8 KB in flight per wave
constexpr int ROWS_PER_BLOCK = 66;                        // ceil(65536 / 1000)

__device__ __forceinline__ float huber_f(float h) {
    float hc = fmaxf(fminf(h, 2.0f), 0.0f);               // v_med3_f32
    return hc * fmaf(h, 2.0f, -hc);
}

__global__ __launch_bounds__(BLOCK) void mhl_main(const f4* __restrict__ in,
                                                  const float* __restrict__ in_f,
                                                  const int* __restrict__ tgt,
                                                  float* __restrict__ partial) {
    float acc = 0.0f;

    // correction gathers folded into the main blocks (latency hides under the stream):
    // block b owns rows [b*66, b*66+66) ∩ [0, 65536), one gather per thread (lanes 0..65)
    if (threadIdx.x < ROWS_PER_BLOCK) {
        int r = blockIdx.x * ROWS_PER_BLOCK + threadIdx.x;
        if (r < N_ROWS) {
            int t = tgt[r];
            float x = in_f[r * N_COLS + t];               // < 65.5M, fits int32
            acc += huber_f(1.0f - x) - huber_f(1.0f + x);
        }
    }

    // main pass: target-free stream, 4 VALU/elem
    int p = blockIdx.x * BLOCK + threadIdx.x;
#pragma unroll 1
    for (int it = 0; it < ITERS / BATCH; ++it) {
        f4 v[BATCH];
#pragma unroll
        for (int j = 0; j < BATCH; ++j)
            v[j] = in[p + j * STRIDE_F4];
#pragma unroll
        for (int j = 0; j < BATCH; ++j) {
#pragma unroll
            for (int e = 0; e < 4; ++e) {
                float h = 1.0f + v[j][e];                 // v_add
                float hc = fmaxf(fminf(h, 2.0f), 0.0f);   // v_med3
                acc = fmaf(hc, fmaf(h, 2.0f, -hc), acc);  // v_fma + v_fmac
            }
        }
        p += BATCH * STRIDE_F4;
    }

    // block reduce -> one partial per block (no atomics, no zeroed output needed)
#pragma unroll
    for (int off = 32; off > 0; off >>= 1)
        acc += __shfl_down(acc, off, 64);

    __shared__ float wsum[BLOCK / 64];
    if ((threadIdx.x & 63) == 0) wsum[threadIdx.x >> 6] = acc;
    __syncthreads();
    if (threadIdx.x == 0)
        partial[blockIdx.x] = wsum[0] + wsum[1] + wsum[2] + wsum[3];
}

__global__ __launch_bounds__(BLOCK) void mhl_reduce(const float* __restrict__ partial,
                                                    float* __restrict__ out) {
    float acc = 0.0f;
    for (int i = threadIdx.x; i < GRID; i += BLOCK)
        acc += partial[i];
#pragma unroll
    for (int off = 32; off > 0; off >>= 1)
        acc += __shfl_down(acc, off, 64);
    __shared__ float wsum[BLOCK / 64];
    if ((threadIdx.x & 63) == 0) wsum[threadIdx.x >> 6] = acc;
    __syncthreads();
    if (threadIdx.x == 0)
        out[0] = (wsum[0] + wsum[1] + wsum[2] + wsum[3]) * (1.0f / (float)N_ROWS);
}

extern "C" void kernel_launch(void* const* d_in, const int* in_sizes, int n_in,
                              void* d_out, int out_size, void* d_ws, size_t ws_size,
                              hipStream_t stream) {
    const f4* in = (const f4*)d_in[0];
    const float* in_f = (const float*)d_in[0];
    const int* tgt = (const int*)d_in[1];
    float* out = (float*)d_out;
    float* partial = (float*)d_ws;                        // 1000 floats = 4 KB of ws

    mhl_main<<<GRID, BLOCK, 0, stream>>>(in, in_f, tgt, partial);
    mhl_reduce<<<1, BLOCK, 0, stream>>>(partial, out);
}